// Round 11
// baseline (4727.700 us; speedup 1.0000x reference)
//
#include <hip/hip_runtime.h>
#include <math.h>

#define N_PTS       40000
#define N_ANCH      4000     // ceil(0.1 * 40000)
#define KNN         20
#define NB          32       // fps blocks
#define BT          256      // threads per block (all blocks)
#define NWAVES      128                // fps waves
#define STRIDE      (NB * BT)          // 8192 = 2^13
#define PPT         5                  // 8192*5 = 40960 >= 40000
#define TW          8                  // published candidates per WAVE
#define POOL        (NWAVES * TW)      // 1024
#define RSLOTS      (POOL / 64)        // 16 readback entries per lane
#define CCAP        10                 // compacted capacity/lane (640 entries)

typedef unsigned long long ull;

#define LD_RLX(p)    __hip_atomic_load((p),  __ATOMIC_RELAXED, __HIP_MEMORY_SCOPE_AGENT)
#define ST_REL(p,v)  __hip_atomic_store((p), (v), __ATOMIC_RELEASE, __HIP_MEMORY_SCOPE_AGENT)
#define ST_RLX(p,v)  __hip_atomic_store((p), (v), __ATOMIC_RELAXED, __HIP_MEMORY_SCOPE_AGENT)

// Workspace layout:
//   off     0 : double acc               (zeroed)
//   off    64 : int flag[128]            (zeroed; per-wave monotone batch counters)
//   off  1024 : ull slots[2][1024][2]    (parity x pool x {f64 bits, idx}; 32 KB)
//   off 33792 : int anchors[4000]        (memset 0xFF -> -1)

__device__ __forceinline__ double dist64(double px, double py, double pz,
                                         double wx, double wy, double wz) {
  double dx = px - wx, dy = py - wy, dz = pz - wz;
  return dx * dx + dy * dy + dz * dz;
}

// monotone u32 bucket key from f64 (order-preserving on high-32 buckets)
__device__ __forceinline__ unsigned key32(double v) {
  unsigned hi = (unsigned)__double2hiint(v);
  return (hi & 0x80000000u) ? ~hi : (hi | 0x80000000u);
}

// wave-wide max of u32 via DPP (VALU only); returns wave-uniform max
__device__ __forceinline__ unsigned wave_umax_dpp(unsigned x) {
#define DPP_STEP(ctrl) { unsigned y = (unsigned)__builtin_amdgcn_update_dpp( \
      0, (int)x, ctrl, 0xf, 0xf, true); x = (y > x) ? y : x; }
  DPP_STEP(0x111)  // row_shr:1
  DPP_STEP(0x112)  // row_shr:2
  DPP_STEP(0x114)  // row_shr:4
  DPP_STEP(0x118)  // row_shr:8
  DPP_STEP(0x142)  // row_bcast:15
  DPP_STEP(0x143)  // row_bcast:31
#undef DPP_STEP
  return (unsigned)__builtin_amdgcn_readlane((int)x, 63);
}

__device__ __forceinline__ int rl_i(int v, int l) { return __builtin_amdgcn_readlane(v, l); }
__device__ __forceinline__ double rl_d(double v, int l) {
  int lo = __builtin_amdgcn_readlane(__double2loint(v), l);
  int hi = __builtin_amdgcn_readlane(__double2hiint(v), l);
  return __hiloint2double(hi, lo);
}

// exact wave argmax (value desc, idx asc) — rare fallback path
__device__ __forceinline__ void wave_argmax_exact(double& wv, int& wix) {
#pragma unroll
  for (int off = 1; off < 64; off <<= 1) {
    double ov = __shfl_xor(wv, off);
    int    oi = __shfl_xor(wix, off);
    bool bt = (ov > wv) || (ov == wv && oi < wix);
    wv = bt ? ov : wv; wix = bt ? oi : wix;
  }
}

// wave winner of (v desc, idx asc): wave-uniform (wkey, wlane, widx). Exact.
__device__ __forceinline__ void wave_pick(double v, int idx,
                                          unsigned& wkey, int& wlane, int& widx) {
  unsigned k = key32(v);
  unsigned M = wave_umax_dpp(k);
  ull mask = __ballot(k == M);
  if (__popcll(mask) == 1) {
    wlane = __ffsll(mask) - 1;
    widx  = rl_i(idx, wlane);
    wkey  = M;
  } else {
    double wv = v; int wi = idx;
    wave_argmax_exact(wv, wi);
    widx = wi;
    wkey = key32(wv);
    ull m2 = __ballot(idx == widx);
    wlane = __ffsll(m2) - 1;
  }
}

struct FpsSm {                 // per-wave-private compaction buffers (61.4 KB)
  double lv[4][CCAP * 64];
  float  lc[4][CCAP * 64][3];
  int    li[4][CCAP * 64];
};
struct KnnSm { ull m4[4]; ull g; int w[KNN]; int ai; };
union Smem { FpsSm f; KnnSm k; };

// ============== symmetric 3x3: eigenvector of largest eigenvalue ===========
__device__ static inline void eig3_maxvec(double xx, double xy, double xz,
                                          double yy, double yz, double zz,
                                          double& v0, double& v1, double& v2) {
  double q  = (xx + yy + zz) / 3.0;
  double p1 = xy * xy + xz * xz + yz * yz;
  double a00 = xx - q, a11 = yy - q, a22 = zz - q;
  double p2 = a00 * a00 + a11 * a11 + a22 * a22 + 2.0 * p1;
  if (p2 < 1e-300) { v0 = 1.0; v1 = 0.0; v2 = 0.0; return; }
  double p   = sqrt(p2 / 6.0);
  double inv = 1.0 / p;
  double b00 = a00 * inv, b01 = xy * inv, b02 = xz * inv;
  double b11 = a11 * inv, b12 = yz * inv, b22 = a22 * inv;
  double detB = b00 * (b11 * b22 - b12 * b12)
              - b01 * (b01 * b22 - b12 * b02)
              + b02 * (b01 * b12 - b11 * b02);
  double r = fmin(1.0, fmax(-1.0, detB * 0.5));
  double phi = acos(r) / 3.0;
  double lam = q + 2.0 * p * cos(phi);   // largest eigenvalue

  double r0x = xx - lam, r0y = xy,       r0z = xz;
  double r1x = xy,       r1y = yy - lam, r1z = yz;
  double r2x = xz,       r2y = yz,       r2z = zz - lam;
  double c0x = r0y * r1z - r0z * r1y, c0y = r0z * r1x - r0x * r1z, c0z = r0x * r1y - r0y * r1x;
  double c1x = r0y * r2z - r0z * r2y, c1y = r0z * r2x - r0x * r2z, c1z = r0x * r2y - r0y * r2x;
  double c2x = r1y * r2z - r1z * r2y, c2y = r1z * r2x - r1x * r2z, c2z = r1x * r2y - r1y * r2x;
  double n0 = c0x * c0x + c0y * c0y + c0z * c0z;
  double n1 = c1x * c1x + c1y * c1y + c1z * c1z;
  double n2 = c2x * c2x + c2y * c2y + c2z * c2z;
  double bx = c0x, by = c0y, bz = c0z, bn = n0;
  if (n1 > bn) { bx = c1x; by = c1y; bz = c1z; bn = n1; }
  if (n2 > bn) { bx = c2x; by = c2y; bz = c2z; bn = n2; }
  if (bn < 1e-280) { v0 = 1.0; v1 = 0.0; v2 = 0.0; return; }
  double s = 1.0 / sqrt(bn);
  v0 = bx * s; v1 = by * s; v2 = bz * s;
}

// ===========================================================================
__global__ __launch_bounds__(BT, 2) void fps_knn_kernel(
    const float* __restrict__ pos, const float* __restrict__ vec_pred,
    int* __restrict__ flag, ull* __restrict__ slots,
    int* __restrict__ anchors, double* __restrict__ acc) {
  __shared__ Smem sm;
  const int t    = threadIdx.x;
  const int lane = t & 63;
  const int wave = t >> 6;

  if (blockIdx.x < NB) {
    // ================== FPS (batched, wave-autonomous) ====================
    const int b    = blockIdx.x;
    const int gtid = b * BT + t;
    const int gw   = b * 4 + wave;     // global wave id, 0..127

    double pdx[PPT], pdy[PPT], pdz[PPT], md[PPT];   // f64 coords in regs
    const double a0x = (double)pos[0], a0y = (double)pos[1], a0z = (double)pos[2];
#pragma unroll
    for (int k = 0; k < PPT; ++k) {
      int i = gtid + k * STRIDE;
      if (i < N_PTS) {
        pdx[k] = (double)pos[3 * i];
        pdy[k] = (double)pos[3 * i + 1];
        pdz[k] = (double)pos[3 * i + 2];
        md[k]  = dist64(pdx[k], pdy[k], pdz[k], a0x, a0y, a0z);
      } else {
        pdx[k] = 0.0; pdy[k] = 0.0; pdz[k] = 0.0;
        md[k]  = -1.0e300;   // pad: never beats real md >= 0
      }
    }
    if (b == 0 && t == 0) ST_RLX(anchors + 0, 0);

    double bv = -1.0e301; int bi = 0x7fffffff;
#pragma unroll
    for (int k = 0; k < PPT; ++k) {
      int i = gtid + k * STRIDE;
      bool bt = (md[k] > bv) || (md[k] == bv && i < bi);
      bv = bt ? md[k] : bv; bi = bt ? i : bi;
    }

    int nsel  = 1;
    int batch = 0;
#pragma unroll 1
    while (nsel < N_ANCH) {
      batch++;
      const int par = batch & 1;

      // ---- per-wave top-8 extraction (exact lex order) ----
      unsigned cons = 0;
      double pv = -1.0e301; int pix = 0;
#pragma unroll 1
      for (int r = 0; r < TW; ++r) {
        unsigned wkey; int wlane, widx;
        wave_pick(bv, bi, wkey, wlane, widx);
        double wval = rl_d(bv, wlane);
        if (lane == wlane && bi != 0x7fffffff) {
          cons |= 1u << ((unsigned)(bi - gtid) >> 13);
          bv = -1.0e301; bi = 0x7fffffff;
#pragma unroll
          for (int k = 0; k < PPT; ++k) {
            if (!((cons >> k) & 1u)) {
              int i = gtid + k * STRIDE;
              bool bt = (md[k] > bv) || (md[k] == bv && i < bi);
              bv = bt ? md[k] : bv; bi = bt ? i : bi;
            }
          }
        }
        if (lane == r) { pv = wval; pix = widx; }
      }

      // ---- publish: relaxed slot stores; lane0 release flag orders them ----
      if (lane < TW) {
        ull* sp = slots + (ull)((par * POOL + gw * TW + lane) * 2);
        ST_RLX(sp,     (ull)__double_as_longlong(pv));
        ST_RLX(sp + 1, (ull)(unsigned)pix);
      }
      if (lane == 0) ST_REL(flag + gw, batch);   // s_waitcnt vmcnt(0) + store

      // ---- poll all 128 wave-flags (relaxed; no cache invalidation) ----
      for (;;) {
        int f0 = LD_RLX(flag + lane);
        int f1 = LD_RLX(flag + 64 + lane);
        if (__ballot((f0 >= batch) && (f1 >= batch)) == ~0ull) break;
        __builtin_amdgcn_s_sleep(1);
      }
      __builtin_amdgcn_sched_barrier(0);   // no compiler motion across the poll

      // ---- readback pool: {f64, idx} x 16 entries/lane ----
      double cv[RSLOTS]; int ci[RSLOTS];
#pragma unroll
      for (int j = 0; j < RSLOTS; ++j) {
        ull* sp = slots + (ull)((par * POOL + lane + 64 * j) * 2);
        cv[j] = __longlong_as_double((long long)LD_RLX(sp));
        ci[j] = (int)(unsigned)LD_RLX(sp + 1);
      }

      // ---- bucket keys; Mkey (global max bucket) and BmaxKey ----
      // entry e = lane + 64*j has tw = e & 7 = lane & 7, so lanes with
      // (lane&7)==7 hold exactly the waves' 8th (smallest) published values.
      unsigned kj[RSLOTS];
      unsigned lkmax = 0;
#pragma unroll
      for (int j = 0; j < RSLOTS; ++j) {
        kj[j] = key32(cv[j]);
        lkmax = (kj[j] > lkmax) ? kj[j] : lkmax;
      }
      const unsigned Mkey    = wave_umax_dpp(lkmax);
      const unsigned BmaxKey = wave_umax_dpp(((lane & 7) == 7) ? lkmax : 0u);

      // pre-pass: live count (entries with bucket > BmaxKey)
      int live_n = 0;
#pragma unroll
      for (int j = 0; j < RSLOTS; ++j)
        live_n += (int)__popcll(__ballot(kj[j] > BmaxKey));

      int cap = N_ANCH - nsel;
      int S = 0;

      if (Mkey > BmaxKey && live_n <= CCAP * 64) {
        // -------- typical path: compact live entries into LDS --------------
        int base = 0;
#pragma unroll
        for (int j = 0; j < RSLOTS; ++j) {
          bool live = kj[j] > BmaxKey;
          ull bal = __ballot(live);
          int rank = base + (int)__popcll(bal & ((1ull << lane) - 1ull));
          if (live) {
            sm.f.lv[wave][rank] = cv[j];
            sm.f.li[wave][rank] = ci[j];
            int p = ci[j];
            sm.f.lc[wave][rank][0] = pos[3 * p];
            sm.f.lc[wave][rank][1] = pos[3 * p + 1];
            sm.f.lc[wave][rank][2] = pos[3 * p + 2];
          }
          base += (int)__popcll(bal);
        }

        // load ALL compaction data to registers
        double cv2[CCAP], c2x[CCAP], c2y[CCAP], c2z[CCAP]; int ci2[CCAP];
#pragma unroll
        for (int tt = 0; tt < CCAP; ++tt) {
          if (live_n > tt * 64) {
            int e = tt * 64 + lane;
            bool ok = e < live_n;
            double v  = sm.f.lv[wave][e];
            int    ii = sm.f.li[wave][e];
            float  x  = sm.f.lc[wave][e][0];
            float  y  = sm.f.lc[wave][e][1];
            float  z  = sm.f.lc[wave][e][2];
            cv2[tt] = ok ? v : -1.0e301;
            ci2[tt] = ok ? ii : 0x7fffffff;
            c2x[tt] = ok ? (double)x : 0.0;
            c2y[tt] = ok ? (double)y : 0.0;
            c2z[tt] = ok ? (double)z : 0.0;
          } else {
            cv2[tt] = -1.0e301; ci2[tt] = 0x7fffffff;
            c2x[tt] = 0.0; c2y[tt] = 0.0; c2z[tt] = 0.0;
          }
        }

#pragma unroll 1
        while (S < cap) {
          double wv = cv2[0]; int wix = ci2[0];
          double fx = c2x[0], fy = c2y[0], fz = c2z[0];
#pragma unroll
          for (int tt = 1; tt < CCAP; ++tt) {
            if (live_n > tt * 64) {
              bool bt = (cv2[tt] > wv) || (cv2[tt] == wv && ci2[tt] < wix);
              wv = bt ? cv2[tt] : wv; wix = bt ? ci2[tt] : wix;
              fx = bt ? c2x[tt] : fx; fy = bt ? c2y[tt] : fy; fz = bt ? c2z[tt] : fz;
            }
          }
          unsigned wkey; int wlane, widx;
          wave_pick(wv, wix, wkey, wlane, widx);
          if (S != 0 && !(wkey > BmaxKey)) break;
          double wxd = rl_d(fx, wlane), wyd = rl_d(fy, wlane), wzd = rl_d(fz, wlane);
          if (b == 0 && lane == 0) ST_RLX(anchors + nsel + S, widx);
#pragma unroll
          for (int tt = 0; tt < CCAP; ++tt) {
            if (live_n > tt * 64) {
              cv2[tt] = fmin(cv2[tt], dist64(c2x[tt], c2y[tt], c2z[tt], wxd, wyd, wzd));
              if (ci2[tt] == widx) cv2[tt] = -1.0e301;
            }
          }
          // inline apply to own md slice
#pragma unroll
          for (int k = 0; k < PPT; ++k)
            md[k] = fmin(md[k], dist64(pdx[k], pdy[k], pdz[k], wxd, wyd, wzd));
          S++;
        }
      } else {
        // -------- fallback (bucket tie / overflow; rare): exact slow loop ---
#pragma unroll 1
        while (S < cap) {
          double wv = cv[0]; int wix = ci[0];
#pragma unroll
          for (int j = 1; j < RSLOTS; ++j) {
            bool bt = (cv[j] > wv) || (cv[j] == wv && ci[j] < wix);
            wv = bt ? cv[j] : wv; wix = bt ? ci[j] : wix;
          }
          unsigned wkey; int wlane, widx;
          wave_pick(wv, wix, wkey, wlane, widx);
          if (S != 0 && !(wkey > BmaxKey)) break;
          double wxd = (double)pos[3 * widx];
          double wyd = (double)pos[3 * widx + 1];
          double wzd = (double)pos[3 * widx + 2];
          if (b == 0 && lane == 0) ST_RLX(anchors + nsel + S, widx);
#pragma unroll
          for (int j = 0; j < RSLOTS; ++j) {
            int p = ci[j];
            double d = dist64((double)pos[3 * p], (double)pos[3 * p + 1],
                              (double)pos[3 * p + 2], wxd, wyd, wzd);
            cv[j] = fmin(cv[j], d);
            if (ci[j] == widx) cv[j] = -1.0e301;
          }
#pragma unroll
          for (int k = 0; k < PPT; ++k)
            md[k] = fmin(md[k], dist64(pdx[k], pdy[k], pdz[k], wxd, wyd, wzd));
          S++;
        }
      }
      nsel += S;

      // refresh thread-local argmax
      bv = -1.0e301; bi = 0x7fffffff;
#pragma unroll
      for (int k = 0; k < PPT; ++k) {
        int i = gtid + k * STRIDE;
        bool bt = (md[k] > bv) || (md[k] == bv && i < bi);
        bv = bt ? md[k] : bv; bi = bt ? i : bi;
      }
    }
  } else {
    // ========================= KNN (anchor-polling) =======================
    const int aidx = blockIdx.x - NB;
    if (t == 0) {
      int a = LD_RLX(anchors + aidx);   // relaxed: payload IS the word; pos immutable
      int spin = 1;
      while (a < 0) {
        for (int u = 0; u < spin; ++u) __builtin_amdgcn_s_sleep(32);
        if (spin < 32) spin <<= 1;
        a = LD_RLX(anchors + aidx);
      }
      sm.k.ai = a;
    }
    __syncthreads();
    const int ai = sm.k.ai;
    const float ax = pos[3 * ai], ay = pos[3 * ai + 1], az = pos[3 * ai + 2];

    // per-thread top-20 (u64 keys, static indexing ONLY -> stays in VGPRs)
    ull key[KNN];
#pragma unroll
    for (int s = 0; s < KNN; ++s) key[s] = ~0ull;
    ull kmax = ~0ull; int smax = 0;
#pragma unroll 1
    for (int k = 0; k < (N_PTS + BT - 1) / BT; ++k) {
      int j = k * BT + t;
      if (j < N_PTS) {
        float dx = pos[3 * j] - ax, dy = pos[3 * j + 1] - ay, dz = pos[3 * j + 2] - az;
        float d  = dx * dx + dy * dy + dz * dz;
        ull nk = ((ull)__float_as_uint(d) << 32) | (unsigned)j;
        if (nk < kmax) {
#pragma unroll
          for (int s = 0; s < KNN; ++s) key[s] = (s == smax) ? nk : key[s];
          kmax = 0ull; smax = 0;
#pragma unroll
          for (int s = 0; s < KNN; ++s) {
            bool g = key[s] > kmax;
            kmax = g ? key[s] : kmax;
            smax = g ? s : smax;
          }
        }
      }
    }

    // block-wide merge: 20 extract-min rounds
    ull lmin = ~0ull; int ls = 0;
#pragma unroll
    for (int s = 0; s < KNN; ++s) {
      bool l = key[s] < lmin;
      lmin = l ? key[s] : lmin; ls = l ? s : ls;
    }
#pragma unroll 1
    for (int r = 0; r < KNN; ++r) {
      ull mv = lmin;
#pragma unroll
      for (int off = 32; off >= 1; off >>= 1) {
        ull ov = __shfl_down(mv, off);
        mv = (ov < mv) ? ov : mv;
      }
      if (lane == 0) sm.k.m4[wave] = mv;
      __syncthreads();
      if (t == 0) {
        ull g = sm.k.m4[0];
#pragma unroll
        for (int w = 1; w < 4; ++w) g = (sm.k.m4[w] < g) ? sm.k.m4[w] : g;
        sm.k.g = g;
        sm.k.w[r] = (int)(g & 0xffffffffull);
      }
      __syncthreads();
      ull g = sm.k.g;
      if (lmin == g) {
#pragma unroll
        for (int s = 0; s < KNN; ++s) key[s] = (s == ls) ? ~0ull : key[s];
        lmin = ~0ull; ls = 0;
#pragma unroll
        for (int s = 0; s < KNN; ++s) {
          bool l = key[s] < lmin;
          lmin = l ? key[s] : lmin; ls = l ? s : ls;
        }
      }
    }

    if (t == 0) {
      double mx = 0, my = 0, mz = 0;
      for (int r = 0; r < KNN; ++r) {
        int p = sm.k.w[r];
        mx += (double)pos[3 * p]; my += (double)pos[3 * p + 1]; mz += (double)pos[3 * p + 2];
      }
      mx /= KNN; my /= KNN; mz /= KNN;
      double xx = 0, xy = 0, xz = 0, yy = 0, yz = 0, zz = 0;
      for (int r = 0; r < KNN; ++r) {
        int p = sm.k.w[r];
        double cx = (double)pos[3 * p]     - mx;
        double cy = (double)pos[3 * p + 1] - my;
        double cz = (double)pos[3 * p + 2] - mz;
        xx += cx * cx; xy += cx * cy; xz += cx * cz;
        yy += cy * cy; yz += cy * cz; zz += cz * cz;
      }
      double v0, v1, v2;
      eig3_maxvec(xx, xy, xz, yy, yz, zz, v0, v1, v2);

      double a0 = vec_pred[3 * aidx], a1 = vec_pred[3 * aidx + 1], a2 = vec_pred[3 * aidx + 2];
      double an = sqrt(a0 * a0 + a1 * a1 + a2 * a2);
      double bn = sqrt(v0 * v0 + v1 * v1 + v2 * v2);
      double denom = fmax(an, 1e-8) * fmax(bn, 1e-8);
      double c = fabs((a0 * v0 + a1 * v1 + a2 * v2) / denom);
      atomicAdd(acc, log(c + 1e-6));
    }
  }
}

__global__ void finalize_kernel(const double* __restrict__ acc, float* __restrict__ out) {
  out[0] = (float)(-acc[0] / (double)N_ANCH);
}

// ===========================================================================
extern "C" void kernel_launch(void* const* d_in, const int* in_sizes, int n_in,
                              void* d_out, int out_size, void* d_ws, size_t ws_size,
                              hipStream_t stream) {
  (void)in_sizes; (void)n_in; (void)out_size; (void)ws_size;
  const float* vec_pred = (const float*)d_in[0];
  const float* pos      = (const float*)d_in[1];
  float* out = (float*)d_out;

  char* ws = (char*)d_ws;
  double* acc     = (double*)(ws + 0);
  int*    flag    = (int*)(ws + 64);
  ull*    slots   = (ull*)(ws + 1024);
  int*    anchors = (int*)(ws + 33792);

  hipMemsetAsync(ws, 0, 1024, stream);                   // acc + flags
  hipMemsetAsync(ws + 33792, 0xFF, N_ANCH * 4, stream);  // anchors = -1
  hipLaunchKernelGGL(fps_knn_kernel, dim3(NB + N_ANCH), dim3(BT), 0, stream,
                     pos, vec_pred, flag, slots, anchors, acc);
  hipLaunchKernelGGL(finalize_kernel, dim3(1), dim3(1), 0, stream, acc, out);
}

// Round 12
// 3206.207 us; speedup vs baseline: 1.4745x; 1.4745x over previous
//
#include <hip/hip_runtime.h>
#include <math.h>

#define N_PTS       40000
#define N_ANCH      4000     // ceil(0.1 * 40000)
#define KNN         20
#define NFB         128      // fps blocks (1 wave each)
#define BT          64       // threads per block (all blocks) = 1 wave
#define NWAVES      128                // fps waves
#define STRIDE      (NWAVES * 64)      // 8192 = 2^13
#define PPT         5                  // 8192*5 = 40960 >= 40000
#define TW          4                  // published candidates per WAVE
#define POOL        (NWAVES * TW)      // 512
#define RSLOTS      (POOL / 64)        // 8 readback entries per lane
#define CCAP        6                  // compacted capacity/lane (384 hard bound)

typedef unsigned long long ull;

#define LD_RLX(p)    __hip_atomic_load((p),  __ATOMIC_RELAXED, __HIP_MEMORY_SCOPE_AGENT)
#define ST_REL(p,v)  __hip_atomic_store((p), (v), __ATOMIC_RELEASE, __HIP_MEMORY_SCOPE_AGENT)
#define ST_RLX(p,v)  __hip_atomic_store((p), (v), __ATOMIC_RELAXED, __HIP_MEMORY_SCOPE_AGENT)

// Workspace layout (identical to R8):
//   off     0 : double acc               (zeroed)
//   off    64 : int flag[128]            (zeroed; per-wave monotone batch counters)
//   off  1024 : ull slots[2][512][2]     (parity x pool x {f64 bits, idx}; 16 KB)
//   off 17408 : int anchors[4000]        (memset 0xFF -> -1)

__device__ __forceinline__ double dist64(double px, double py, double pz,
                                         double wx, double wy, double wz) {
  double dx = px - wx, dy = py - wy, dz = pz - wz;
  return dx * dx + dy * dy + dz * dz;
}

// monotone u32 bucket key from f64 (order-preserving on high-32 buckets)
__device__ __forceinline__ unsigned key32(double v) {
  unsigned hi = (unsigned)__double2hiint(v);
  return (hi & 0x80000000u) ? ~hi : (hi | 0x80000000u);
}

// wave-wide max of u32 via DPP (VALU only); returns wave-uniform max
__device__ __forceinline__ unsigned wave_umax_dpp(unsigned x) {
#define DPP_STEP(ctrl) { unsigned y = (unsigned)__builtin_amdgcn_update_dpp( \
      0, (int)x, ctrl, 0xf, 0xf, true); x = (y > x) ? y : x; }
  DPP_STEP(0x111)  // row_shr:1
  DPP_STEP(0x112)  // row_shr:2
  DPP_STEP(0x114)  // row_shr:4
  DPP_STEP(0x118)  // row_shr:8
  DPP_STEP(0x142)  // row_bcast:15
  DPP_STEP(0x143)  // row_bcast:31
#undef DPP_STEP
  return (unsigned)__builtin_amdgcn_readlane((int)x, 63);
}

__device__ __forceinline__ int rl_i(int v, int l) { return __builtin_amdgcn_readlane(v, l); }
__device__ __forceinline__ double rl_d(double v, int l) {
  int lo = __builtin_amdgcn_readlane(__double2loint(v), l);
  int hi = __builtin_amdgcn_readlane(__double2hiint(v), l);
  return __hiloint2double(hi, lo);
}

// exact wave argmax (value desc, idx asc) — rare fallback path
__device__ __forceinline__ void wave_argmax_exact(double& wv, int& wix) {
#pragma unroll
  for (int off = 1; off < 64; off <<= 1) {
    double ov = __shfl_xor(wv, off);
    int    oi = __shfl_xor(wix, off);
    bool bt = (ov > wv) || (ov == wv && oi < wix);
    wv = bt ? ov : wv; wix = bt ? oi : wix;
  }
}

// wave winner of (v desc, idx asc): wave-uniform (wkey, wlane, widx). Exact.
__device__ __forceinline__ void wave_pick(double v, int idx,
                                          unsigned& wkey, int& wlane, int& widx) {
  unsigned k = key32(v);
  unsigned M = wave_umax_dpp(k);
  ull mask = __ballot(k == M);
  if (__popcll(mask) == 1) {
    wlane = __ffsll(mask) - 1;
    widx  = rl_i(idx, wlane);
    wkey  = M;
  } else {
    double wv = v; int wi = idx;
    wave_argmax_exact(wv, wi);
    widx = wi;
    wkey = key32(wv);
    ull m2 = __ballot(idx == widx);
    wlane = __ffsll(m2) - 1;
  }
}

struct FpsSm {                 // single-wave compaction buffers (~9.3 KB)
  double lv[CCAP * 64];
  float  lc[CCAP * 64][3];
  int    li[CCAP * 64];
};
struct KnnSm { int w[KNN]; };
union Smem { FpsSm f; KnnSm k; };

// ============== symmetric 3x3: eigenvector of largest eigenvalue ===========
__device__ static inline void eig3_maxvec(double xx, double xy, double xz,
                                          double yy, double yz, double zz,
                                          double& v0, double& v1, double& v2) {
  double q  = (xx + yy + zz) / 3.0;
  double p1 = xy * xy + xz * xz + yz * yz;
  double a00 = xx - q, a11 = yy - q, a22 = zz - q;
  double p2 = a00 * a00 + a11 * a11 + a22 * a22 + 2.0 * p1;
  if (p2 < 1e-300) { v0 = 1.0; v1 = 0.0; v2 = 0.0; return; }
  double p   = sqrt(p2 / 6.0);
  double inv = 1.0 / p;
  double b00 = a00 * inv, b01 = xy * inv, b02 = xz * inv;
  double b11 = a11 * inv, b12 = yz * inv, b22 = a22 * inv;
  double detB = b00 * (b11 * b22 - b12 * b12)
              - b01 * (b01 * b22 - b12 * b02)
              + b02 * (b01 * b12 - b11 * b02);
  double r = fmin(1.0, fmax(-1.0, detB * 0.5));
  double phi = acos(r) / 3.0;
  double lam = q + 2.0 * p * cos(phi);   // largest eigenvalue

  double r0x = xx - lam, r0y = xy,       r0z = xz;
  double r1x = xy,       r1y = yy - lam, r1z = yz;
  double r2x = xz,       r2y = yz,       r2z = zz - lam;
  double c0x = r0y * r1z - r0z * r1y, c0y = r0z * r1x - r0x * r1z, c0z = r0x * r1y - r0y * r1x;
  double c1x = r0y * r2z - r0z * r2y, c1y = r0z * r2x - r0x * r2z, c1z = r0x * r2y - r0y * r2x;
  double c2x = r1y * r2z - r1z * r2y, c2y = r1z * r2x - r1x * r2z, c2z = r1x * r2y - r1y * r2x;
  double n0 = c0x * c0x + c0y * c0y + c0z * c0z;
  double n1 = c1x * c1x + c1y * c1y + c1z * c1z;
  double n2 = c2x * c2x + c2y * c2y + c2z * c2z;
  double bx = c0x, by = c0y, bz = c0z, bn = n0;
  if (n1 > bn) { bx = c1x; by = c1y; bz = c1z; bn = n1; }
  if (n2 > bn) { bx = c2x; by = c2y; bz = c2z; bn = n2; }
  if (bn < 1e-280) { v0 = 1.0; v1 = 0.0; v2 = 0.0; return; }
  double s = 1.0 / sqrt(bn);
  v0 = bx * s; v1 = by * s; v2 = bz * s;
}

// ===========================================================================
__global__ __launch_bounds__(BT, 2) void fps_knn_kernel(
    const float* __restrict__ pos, const float* __restrict__ vec_pred,
    int* __restrict__ flag, ull* __restrict__ slots,
    int* __restrict__ anchors, double* __restrict__ acc) {
  __shared__ Smem sm;
  const int lane = threadIdx.x & 63;

  if (blockIdx.x < NFB) {
    // ============ FPS: one wave per block, wave-autonomous ================
    const int gw   = blockIdx.x;       // global wave id, 0..127
    const int gtid = gw * 64 + lane;

    double pdx[PPT], pdy[PPT], pdz[PPT], md[PPT];   // f64 coords in regs
    const double a0x = (double)pos[0], a0y = (double)pos[1], a0z = (double)pos[2];
#pragma unroll
    for (int k = 0; k < PPT; ++k) {
      int i = gtid + k * STRIDE;
      if (i < N_PTS) {
        pdx[k] = (double)pos[3 * i];
        pdy[k] = (double)pos[3 * i + 1];
        pdz[k] = (double)pos[3 * i + 2];
        md[k]  = dist64(pdx[k], pdy[k], pdz[k], a0x, a0y, a0z);
      } else {
        pdx[k] = 0.0; pdy[k] = 0.0; pdz[k] = 0.0;
        md[k]  = -1.0e300;   // pad: never beats real md >= 0
      }
    }
    if (gw == 0 && lane == 0) ST_RLX(anchors + 0, 0);

    double bv = -1.0e301; int bi = 0x7fffffff;
#pragma unroll
    for (int k = 0; k < PPT; ++k) {
      int i = gtid + k * STRIDE;
      bool bt = (md[k] > bv) || (md[k] == bv && i < bi);
      bv = bt ? md[k] : bv; bi = bt ? i : bi;
    }

    int nsel  = 1;
    int batch = 0;
#pragma unroll 1
    while (nsel < N_ANCH) {
      batch++;
      const int par = batch & 1;

      // ---- per-wave top-4 extraction (exact lex order) ----
      unsigned cons = 0;
      double pv = -1.0e301; int pix = 0;
#pragma unroll 1
      for (int r = 0; r < TW; ++r) {
        unsigned wkey; int wlane, widx;
        wave_pick(bv, bi, wkey, wlane, widx);
        double wval = rl_d(bv, wlane);
        if (lane == wlane && bi != 0x7fffffff) {
          cons |= 1u << ((unsigned)(bi - gtid) >> 13);   // STRIDE = 2^13
          bv = -1.0e301; bi = 0x7fffffff;
#pragma unroll
          for (int k = 0; k < PPT; ++k) {
            if (!((cons >> k) & 1u)) {
              int i = gtid + k * STRIDE;
              bool bt = (md[k] > bv) || (md[k] == bv && i < bi);
              bv = bt ? md[k] : bv; bi = bt ? i : bi;
            }
          }
        }
        if (lane == r) { pv = wval; pix = widx; }
      }

      // ---- publish: relaxed slot stores; lane0 release flag orders them ----
      if (lane < TW) {
        ull* sp = slots + (ull)((par * POOL + gw * TW + lane) * 2);
        ST_RLX(sp,     (ull)__double_as_longlong(pv));
        ST_RLX(sp + 1, (ull)(unsigned)pix);
      }
      if (lane == 0) ST_REL(flag + gw, batch);   // s_waitcnt vmcnt(0) + store

      // ---- poll all 128 wave-flags (relaxed; no cache invalidation) ----
      for (;;) {
        int f0 = LD_RLX(flag + lane);
        int f1 = LD_RLX(flag + 64 + lane);
        if (__ballot((f0 >= batch) && (f1 >= batch)) == ~0ull) break;
        __builtin_amdgcn_s_sleep(1);
      }
      __builtin_amdgcn_sched_barrier(0);   // no compiler motion across the poll

      // ---- readback pool: {f64, idx} x 8 entries/lane ----
      double cv[RSLOTS]; int ci[RSLOTS];
#pragma unroll
      for (int j = 0; j < RSLOTS; ++j) {
        ull* sp = slots + (ull)((par * POOL + lane + 64 * j) * 2);
        cv[j] = __longlong_as_double((long long)LD_RLX(sp));
        ci[j] = (int)(unsigned)LD_RLX(sp + 1);
      }

      // ---- bucket keys; Mkey (global max bucket) and BmaxKey ----
      unsigned kj[RSLOTS];
      unsigned lkmax = 0;
#pragma unroll
      for (int j = 0; j < RSLOTS; ++j) {
        kj[j] = key32(cv[j]);
        lkmax = (kj[j] > lkmax) ? kj[j] : lkmax;
      }
      const unsigned Mkey    = wave_umax_dpp(lkmax);
      const unsigned BmaxKey = wave_umax_dpp(((lane & 3) == 3) ? lkmax : 0u);

      int cap = N_ANCH - nsel;
      int S = 0;

      if (Mkey > BmaxKey) {
        // -------- typical path: compact live entries (bucket > BmaxKey) ----
        int base = 0;
#pragma unroll
        for (int j = 0; j < RSLOTS; ++j) {
          bool live = kj[j] > BmaxKey;
          ull bal = __ballot(live);
          int rank = base + (int)__popcll(bal & ((1ull << lane) - 1ull));
          if (live) {
            sm.f.lv[rank] = cv[j];
            sm.f.li[rank] = ci[j];
            int p = ci[j];
            sm.f.lc[rank][0] = pos[3 * p];
            sm.f.lc[rank][1] = pos[3 * p + 1];
            sm.f.lc[rank][2] = pos[3 * p + 2];
          }
          base += (int)__popcll(bal);
        }
        const int live_n = base;   // wave-uniform, 1..384

        // load ALL compaction data to registers
        double cv2[CCAP], c2x[CCAP], c2y[CCAP], c2z[CCAP]; int ci2[CCAP];
#pragma unroll
        for (int tt = 0; tt < CCAP; ++tt) {
          if (live_n > tt * 64) {
            int e = tt * 64 + lane;
            bool ok = e < live_n;
            double v  = sm.f.lv[e];
            int    ii = sm.f.li[e];
            float  x  = sm.f.lc[e][0];
            float  y  = sm.f.lc[e][1];
            float  z  = sm.f.lc[e][2];
            cv2[tt] = ok ? v : -1.0e301;
            ci2[tt] = ok ? ii : 0x7fffffff;
            c2x[tt] = ok ? (double)x : 0.0;
            c2y[tt] = ok ? (double)y : 0.0;
            c2z[tt] = ok ? (double)z : 0.0;
          } else {
            cv2[tt] = -1.0e301; ci2[tt] = 0x7fffffff;
            c2x[tt] = 0.0; c2y[tt] = 0.0; c2z[tt] = 0.0;
          }
        }

#pragma unroll 1
        while (S < cap) {
          double wv = cv2[0]; int wix = ci2[0];
          double fx = c2x[0], fy = c2y[0], fz = c2z[0];
#pragma unroll
          for (int tt = 1; tt < CCAP; ++tt) {
            if (live_n > tt * 64) {
              bool bt = (cv2[tt] > wv) || (cv2[tt] == wv && ci2[tt] < wix);
              wv = bt ? cv2[tt] : wv; wix = bt ? ci2[tt] : wix;
              fx = bt ? c2x[tt] : fx; fy = bt ? c2y[tt] : fy; fz = bt ? c2z[tt] : fz;
            }
          }
          unsigned wkey; int wlane, widx;
          wave_pick(wv, wix, wkey, wlane, widx);
          if (S != 0 && !(wkey > BmaxKey)) break;
          double wxd = rl_d(fx, wlane), wyd = rl_d(fy, wlane), wzd = rl_d(fz, wlane);
          if (gw == 0 && lane == 0) ST_RLX(anchors + nsel + S, widx);
#pragma unroll
          for (int tt = 0; tt < CCAP; ++tt) {
            if (live_n > tt * 64) {
              cv2[tt] = fmin(cv2[tt], dist64(c2x[tt], c2y[tt], c2z[tt], wxd, wyd, wzd));
              if (ci2[tt] == widx) cv2[tt] = -1.0e301;
            }
          }
          // inline apply to own md slice
#pragma unroll
          for (int k = 0; k < PPT; ++k)
            md[k] = fmin(md[k], dist64(pdx[k], pdy[k], pdz[k], wxd, wyd, wzd));
          S++;
        }
      } else {
        // -------- fallback (bucket tie at Bmax; ~never): exact slow loop ---
#pragma unroll 1
        while (S < cap) {
          double wv = cv[0]; int wix = ci[0];
#pragma unroll
          for (int j = 1; j < RSLOTS; ++j) {
            bool bt = (cv[j] > wv) || (cv[j] == wv && ci[j] < wix);
            wv = bt ? cv[j] : wv; wix = bt ? ci[j] : wix;
          }
          unsigned wkey; int wlane, widx;
          wave_pick(wv, wix, wkey, wlane, widx);
          if (S != 0 && !(wkey > BmaxKey)) break;
          double wxd = (double)pos[3 * widx];
          double wyd = (double)pos[3 * widx + 1];
          double wzd = (double)pos[3 * widx + 2];
          if (gw == 0 && lane == 0) ST_RLX(anchors + nsel + S, widx);
#pragma unroll
          for (int j = 0; j < RSLOTS; ++j) {
            int p = ci[j];
            double d = dist64((double)pos[3 * p], (double)pos[3 * p + 1],
                              (double)pos[3 * p + 2], wxd, wyd, wzd);
            cv[j] = fmin(cv[j], d);
            if (ci[j] == widx) cv[j] = -1.0e301;
          }
#pragma unroll
          for (int k = 0; k < PPT; ++k)
            md[k] = fmin(md[k], dist64(pdx[k], pdy[k], pdz[k], wxd, wyd, wzd));
          S++;
        }
      }
      nsel += S;

      // refresh thread-local argmax
      bv = -1.0e301; bi = 0x7fffffff;
#pragma unroll
      for (int k = 0; k < PPT; ++k) {
        int i = gtid + k * STRIDE;
        bool bt = (md[k] > bv) || (md[k] == bv && i < bi);
        bv = bt ? md[k] : bv; bi = bt ? i : bi;
      }
    }
  } else {
    // =============== KNN: one wave per anchor (no barriers) ===============
    const int aidx = blockIdx.x - NFB;
    int a = -1;
    for (;;) {
      if (lane == 0) a = LD_RLX(anchors + aidx);
      a = __shfl(a, 0);
      if (a >= 0) break;
      __builtin_amdgcn_s_sleep(32);
    }
    const int ai = a;
    const float ax = pos[3 * ai], ay = pos[3 * ai + 1], az = pos[3 * ai + 2];

    // per-lane top-20 (u64 keys, static indexing ONLY -> stays in VGPRs)
    ull key[KNN];
#pragma unroll
    for (int s = 0; s < KNN; ++s) key[s] = ~0ull;
    ull kmax = ~0ull; int smax = 0;
#pragma unroll 1
    for (int k = 0; k < N_PTS / 64; ++k) {   // 625 candidates per lane, exact
      int j = (k << 6) + lane;
      float dx = pos[3 * j] - ax, dy = pos[3 * j + 1] - ay, dz = pos[3 * j + 2] - az;
      float d  = dx * dx + dy * dy + dz * dz;
      ull nk = ((ull)__float_as_uint(d) << 32) | (unsigned)j;
      if (nk < kmax) {
#pragma unroll
        for (int s = 0; s < KNN; ++s) key[s] = (s == smax) ? nk : key[s];
        kmax = 0ull; smax = 0;
#pragma unroll
        for (int s = 0; s < KNN; ++s) {
          bool g = key[s] > kmax;
          kmax = g ? key[s] : kmax;
          smax = g ? s : smax;
        }
      }
    }

    // wave-wide merge: 20 extract-min rounds (shuffle butterfly, no LDS sync)
    ull lmin = ~0ull; int ls = 0;
#pragma unroll
    for (int s = 0; s < KNN; ++s) {
      bool l = key[s] < lmin;
      lmin = l ? key[s] : lmin; ls = l ? s : ls;
    }
#pragma unroll 1
    for (int r = 0; r < KNN; ++r) {
      ull g = lmin;
#pragma unroll
      for (int off = 1; off < 64; off <<= 1) {
        ull ov = __shfl_xor(g, off);
        g = (ov < g) ? ov : g;
      }
      if (lane == 0) sm.k.w[r] = (int)(g & 0xffffffffull);
      if (lmin == g) {          // unique owner consumes & rescans (all static)
#pragma unroll
        for (int s = 0; s < KNN; ++s) key[s] = (s == ls) ? ~0ull : key[s];
        lmin = ~0ull; ls = 0;
#pragma unroll
        for (int s = 0; s < KNN; ++s) {
          bool l = key[s] < lmin;
          lmin = l ? key[s] : lmin; ls = l ? s : ls;
        }
      }
    }

    if (lane == 0) {
      double mx = 0, my = 0, mz = 0;
      for (int r = 0; r < KNN; ++r) {
        int p = sm.k.w[r];
        mx += (double)pos[3 * p]; my += (double)pos[3 * p + 1]; mz += (double)pos[3 * p + 2];
      }
      mx /= KNN; my /= KNN; mz /= KNN;
      double xx = 0, xy = 0, xz = 0, yy = 0, yz = 0, zz = 0;
      for (int r = 0; r < KNN; ++r) {
        int p = sm.k.w[r];
        double cx = (double)pos[3 * p]     - mx;
        double cy = (double)pos[3 * p + 1] - my;
        double cz = (double)pos[3 * p + 2] - mz;
        xx += cx * cx; xy += cx * cy; xz += cx * cz;
        yy += cy * cy; yz += cy * cz; zz += cz * cz;
      }
      double v0, v1, v2;
      eig3_maxvec(xx, xy, xz, yy, yz, zz, v0, v1, v2);

      double a0 = vec_pred[3 * aidx], a1 = vec_pred[3 * aidx + 1], a2 = vec_pred[3 * aidx + 2];
      double an = sqrt(a0 * a0 + a1 * a1 + a2 * a2);
      double bn = sqrt(v0 * v0 + v1 * v1 + v2 * v2);
      double denom = fmax(an, 1e-8) * fmax(bn, 1e-8);
      double c = fabs((a0 * v0 + a1 * v1 + a2 * v2) / denom);
      atomicAdd(acc, log(c + 1e-6));
    }
  }
}

__global__ void finalize_kernel(const double* __restrict__ acc, float* __restrict__ out) {
  out[0] = (float)(-acc[0] / (double)N_ANCH);
}

// ===========================================================================
extern "C" void kernel_launch(void* const* d_in, const int* in_sizes, int n_in,
                              void* d_out, int out_size, void* d_ws, size_t ws_size,
                              hipStream_t stream) {
  (void)in_sizes; (void)n_in; (void)out_size; (void)ws_size;
  const float* vec_pred = (const float*)d_in[0];
  const float* pos      = (const float*)d_in[1];
  float* out = (float*)d_out;

  char* ws = (char*)d_ws;
  double* acc     = (double*)(ws + 0);
  int*    flag    = (int*)(ws + 64);
  ull*    slots   = (ull*)(ws + 1024);
  int*    anchors = (int*)(ws + 17408);

  hipMemsetAsync(ws, 0, 1024, stream);                   // acc + flags
  hipMemsetAsync(ws + 17408, 0xFF, N_ANCH * 4, stream);  // anchors = -1
  hipLaunchKernelGGL(fps_knn_kernel, dim3(NFB + N_ANCH), dim3(BT), 0, stream,
                     pos, vec_pred, flag, slots, anchors, acc);
  hipLaunchKernelGGL(finalize_kernel, dim3(1), dim3(1), 0, stream, acc, out);
}